// Round 1
// baseline (555.881 us; speedup 1.0000x reference)
//
#include <hip/hip_runtime.h>
#include <hip/hip_cooperative_groups.h>

namespace cg = cooperative_groups;

#define NB 256            // blocks (1 per CU)
#define BT 512            // threads per block (8 waves)
#define NQUADS (NB * (BT / 4))
#define MSTEPS 8

struct PParams {
  const float* candidate;
  const float* z_past;
  const float* q_w; const float* q_b;
  const float* k_w; const float* k_b;
  const float* v_w; const float* v_b;
  const float* o_w; const float* o_b;
  const float* rel_bias;
  const float* coupling;
  const float* norm_scale;
  float* out;
  float* part;   // 2 * 132 * NB floats (double-buffered partials)
  int L;
};

__device__ __forceinline__ float mish_f(float x) {
  // softplus computed stably: max(x,0) + log1p(exp(-|x|))
  float sp = fmaxf(x, 0.0f) + log1pf(expf(-fabsf(x)));
  return x * tanhf(sp);
}

// Recompute q projection, folded score vectors a_h (pre-scaled by inv_sqrt_d=0.5),
// and the l<64 relative-bias delta table, from the current state sZ.
// Must be called by ALL threads of the block (contains barriers).
__device__ void compute_qar(const PParams& p, int tid,
                            float* sZ, float* sQ, float* sA, float* sRel) {
  if (tid < 32) {
    float acc = p.q_b[tid];
    const float* row = p.q_w + tid * 32;
    #pragma unroll
    for (int c = 0; c < 32; ++c) acc = fmaf(row[c], sZ[c], acc);
    sQ[tid] = acc;
  }
  __syncthreads();
  if (tid < 128) {
    int h = tid >> 5, c = tid & 31;
    float acc = 0.f;
    #pragma unroll
    for (int jj = 0; jj < 8; ++jj)
      acc = fmaf(sQ[8 * h + jj], p.k_w[(8 * h + jj) * 32 + c], acc);
    sA[tid] = 0.5f * acc;               // fold inv_sqrt_d
  }
  if (tid >= 256) {
    // rel-bias delta vs the saturated idx=128 entry (constant part cancels in softmax)
    int t = tid - 256;
    int l = t >> 2, h = t & 3;
    float acc = 0.f;
    #pragma unroll
    for (int jj = 0; jj < 8; ++jj) {
      int jidx = 8 * h + jj;
      acc = fmaf(sQ[jidx],
                 p.rel_bias[(l + 64) * 32 + jidx] - p.rel_bias[128 * 32 + jidx],
                 acc);
    }
    sRel[t] = 0.5f * acc;
  }
  __syncthreads();
}

__global__ __launch_bounds__(BT)
void photonic_kernel(PParams p) {
  cg::grid_group grid = cg::this_grid();

  __shared__ __align__(16) float sZ[32];
  __shared__ float sQ[32];
  __shared__ float sOutV[32];
  __shared__ float sZn[32];
  __shared__ __align__(16) float sA[128];     // a[h][c]
  __shared__ __align__(16) float sRel[256];   // relT[l][h], l<64
  __shared__ float sRed[BT / 64][4][36];      // per-wave reduced (S[4][8] + Z[4]) per quarter
  __shared__ float sSS[128];                  // global-reduced S[h][c]
  __shared__ float sSZ[4];                    // global-reduced Z[h]

  const int tid  = threadIdx.x;
  const int b    = blockIdx.x;
  const int j    = tid & 3;        // quarter (owns columns [8j, 8j+8))
  const int quad = tid >> 2;
  const int gq   = b * (BT / 4) + quad;
  const int wave = tid >> 6;
  const int lane = tid & 63;

  // init state z = candidate (real-interleaved flat 32)
  if (tid < 32) sZ[tid] = p.candidate[tid];
  __syncthreads();
  compute_qar(p, tid, sZ, sQ, sA, sRel);

  for (int iter = 0; iter < MSTEPS; ++iter) {
    // stage my quarter of a[h][*] into registers
    float A[4][8];
    #pragma unroll
    for (int h = 0; h < 4; ++h)
      #pragma unroll
      for (int k = 0; k < 8; ++k)
        A[h][k] = sA[h * 32 + j * 8 + k];

    float S[4][8];
    #pragma unroll
    for (int h = 0; h < 4; ++h)
      #pragma unroll
      for (int k = 0; k < 8; ++k) S[h][k] = 0.f;
    float Zc[4] = {0.f, 0.f, 0.f, 0.f};

    for (int l = gq; l < p.L; l += NQUADS) {
      const float4* zr =
          reinterpret_cast<const float4*>(p.z_past + (size_t)l * 32) + (j * 2);
      float4 za = zr[0];
      float4 zb = zr[1];
      float zv[8] = {za.x, za.y, za.z, za.w, zb.x, zb.y, zb.z, zb.w};

      float d[4] = {0.f, 0.f, 0.f, 0.f};
      #pragma unroll
      for (int h = 0; h < 4; ++h)
        #pragma unroll
        for (int k = 0; k < 8; ++k) d[h] = fmaf(A[h][k], zv[k], d[h]);

      // complete the 32-wide dot across the 4-lane quad
      #pragma unroll
      for (int h = 0; h < 4; ++h) {
        d[h] += __shfl_xor(d[h], 1);
        d[h] += __shfl_xor(d[h], 2);
      }
      if (l < 64) {  // varying rel-bias region (only block 0's first chunk)
        const float4 r = reinterpret_cast<const float4*>(sRel)[l];
        d[0] += r.x; d[1] += r.y; d[2] += r.z; d[3] += r.w;
      }
      float w[4];
      #pragma unroll
      for (int h = 0; h < 4; ++h) { w[h] = __expf(d[h]); Zc[h] += w[h]; }
      #pragma unroll
      for (int h = 0; h < 4; ++h)
        #pragma unroll
        for (int k = 0; k < 8; ++k) S[h][k] = fmaf(w[h], zv[k], S[h][k]);
    }

    // reduce across the 16 quads of each wave (lane%4 == quarter is preserved)
    #pragma unroll
    for (int m = 4; m <= 32; m <<= 1) {
      #pragma unroll
      for (int h = 0; h < 4; ++h) {
        #pragma unroll
        for (int k = 0; k < 8; ++k) S[h][k] += __shfl_xor(S[h][k], m);
        Zc[h] += __shfl_xor(Zc[h], m);
      }
    }
    if ((lane >> 2) == 0) {  // lanes 0..3: lane == quarter j
      #pragma unroll
      for (int h = 0; h < 4; ++h) {
        #pragma unroll
        for (int k = 0; k < 8; ++k) sRed[wave][lane][h * 8 + k] = S[h][k];
        sRed[wave][lane][32 + h] = Zc[h];
      }
    }
    __syncthreads();

    // per-block partials -> global, component-major [comp][block] for coalesced reduce
    float* part = p.part + (iter & 1) * (132 * NB);
    if (tid < 132) {
      float acc = 0.f;
      if (tid < 128) {
        int h = tid >> 5, c = tid & 31;
        int jj = c >> 3, k = c & 7;
        #pragma unroll
        for (int w2 = 0; w2 < BT / 64; ++w2) acc += sRed[w2][jj][h * 8 + k];
        part[(h * 33 + c) * NB + b] = acc;
      } else {
        int h = tid - 128;
        #pragma unroll
        for (int w2 = 0; w2 < BT / 64; ++w2) acc += sRed[w2][0][32 + h];
        part[(h * 33 + 32) * NB + b] = acc;
      }
    }
    grid.sync();

    // every block redundantly reduces all partials (135 KB, L2-resident)
    if (tid < 132) {
      const float4* pp = reinterpret_cast<const float4*>(part + tid * NB);
      float acc = 0.f;
      for (int i = 0; i < NB / 4; ++i) {
        float4 v4 = pp[i];
        acc += (v4.x + v4.y) + (v4.z + v4.w);
      }
      int h = tid / 33, k = tid % 33;
      if (k < 32) sSS[h * 32 + k] = acc; else sSZ[h] = acc;
    }
    __syncthreads();

    // out_flat[j'] = v_w[j',:] @ (S_h / Z_h) + v_b[j']   (h = j'>>3)
    if (tid < 32) {
      int h = tid >> 3;
      float acc = 0.f;
      const float* row = p.v_w + tid * 32;
      #pragma unroll
      for (int c = 0; c < 32; ++c) acc = fmaf(row[c], sSS[h * 32 + c], acc);
      sOutV[tid] = acc / sSZ[h] + p.v_b[tid];
    }
    __syncthreads();
    // mod = o_w @ out + o_b ; z += coupling*mod ; mish
    if (tid < 32) {
      float acc = p.o_b[tid];
      const float* row = p.o_w + tid * 32;
      #pragma unroll
      for (int c = 0; c < 32; ++c) acc = fmaf(row[c], sOutV[c], acc);
      float zv2 = sZ[tid] + p.coupling[0] * acc;
      sZn[tid] = mish_f(zv2);
    }
    __syncthreads();
    // layer-norm over the 16 real / 16 imag components separately
    if (tid < 32) {
      int par = tid & 1;
      float m = 0.f;
      #pragma unroll
      for (int e = 0; e < 16; ++e) m += sZn[2 * e + par];
      m *= (1.f / 16.f);
      float v = 0.f;
      #pragma unroll
      for (int e = 0; e < 16; ++e) { float dd = sZn[2 * e + par] - m; v = fmaf(dd, dd, v); }
      v *= (1.f / 16.f);
      sZ[tid] = (sZn[tid] - m) * rsqrtf(v + 1e-5f) * p.norm_scale[0];
    }
    __syncthreads();
    compute_qar(p, tid, sZ, sQ, sA, sRel);

    if (iter == MSTEPS - 1 && b == 0 && tid < 32) p.out[tid] = sZ[tid];
  }
}

extern "C" void kernel_launch(void* const* d_in, const int* in_sizes, int n_in,
                              void* d_out, int out_size, void* d_ws, size_t ws_size,
                              hipStream_t stream) {
  PParams p;
  p.candidate  = (const float*)d_in[0];
  p.z_past     = (const float*)d_in[1];
  p.q_w = (const float*)d_in[2];  p.q_b = (const float*)d_in[3];
  p.k_w = (const float*)d_in[4];  p.k_b = (const float*)d_in[5];
  p.v_w = (const float*)d_in[6];  p.v_b = (const float*)d_in[7];
  p.o_w = (const float*)d_in[8];  p.o_b = (const float*)d_in[9];
  p.rel_bias   = (const float*)d_in[10];
  p.coupling   = (const float*)d_in[11];
  p.norm_scale = (const float*)d_in[12];
  p.out  = (float*)d_out;
  p.part = (float*)d_ws;
  p.L    = in_sizes[1] / 32;

  void* args[] = { &p };
  hipLaunchCooperativeKernel((const void*)photonic_kernel,
                             dim3(NB), dim3(BT), args, 0, stream);
}